// Round 2
// 208.486 us; speedup vs baseline: 1.0208x; 1.0208x over previous
//
#include <hip/hip_runtime.h>
#include <stdint.h>

// Problem constants (from reference): B=4, N=8192, D=512, H=8, Dh=64
#define SEQ      8192
#define BATCH    4
#define DIM      512
#define MROWS    32768      // BATCH*SEQ
#define CHUNK    64
#define NCHUNK   128        // SEQ / CHUNK
#define NCHAN    2048       // BATCH * DIM
#define NHEAD    8

typedef unsigned short ushort;
typedef unsigned int   uint;
typedef __bf16 bf16x8 __attribute__((ext_vector_type(8)));
typedef float  f32x4  __attribute__((ext_vector_type(4)));
typedef ushort usx8   __attribute__((ext_vector_type(8)));

__device__ __forceinline__ ushort f2bf(float f) {
    unsigned u = __float_as_uint(f);
    unsigned r = (u + 0x7fffu + ((u >> 16) & 1u)) >> 16;   // RNE
    return (ushort)r;
}
__device__ __forceinline__ float bf2f(ushort v) {
    return __uint_as_float(((unsigned)v) << 16);
}

// both weight matrices in one launch; outputs are contiguous in ws
__global__ void weights_to_bf16_kernel(const float* __restrict__ w_in,
                                       const float* __restrict__ w_out,
                                       ushort* __restrict__ dst, int n4each) {
    int i = blockIdx.x * blockDim.x + threadIdx.x;
    if (i >= 2 * n4each) return;
    const float4* src = (i < n4each) ? (const float4*)w_in
                                     : (const float4*)w_out - n4each;
    float4 v = src[i];
    ushort4 r;
    r.x = f2bf(v.x); r.y = f2bf(v.y); r.z = f2bf(v.z); r.w = f2bf(v.w);
    ((ushort4*)dst)[i] = r;
}

// ---------------- bf16 GEMM, 128x256 tile, 8 waves, dbuf, 1 barrier/iter ----
// C[m,n] = sum_k A[m,k]*Bw[n,k] + bias[n]
// AMODE 1: A fp32 in global; reg-staged (dwordx4) + cvt + ds_write
//          -> fuses x fp32->bf16 conversion into GEMM1.
// AMODE 2: A bf16 (z_local); reg-staged + carry-correction
//          a += c_h^{tau+1} * Zin[chunk][ch]  -> fuses the cross-chunk carry
//          application (old scan<true> read-modify-write pass) into GEMM2.
// AMODE 0: A bf16 via global_load_lds (unused this round).
// B (weights, 0.5 MB, L2-resident) always staged via global_load_lds.
// 8 waves as 2(m) x 4(n); each wave 64x64 = 4x4 mfma_16x16x32_bf16.
// Swapped MFMA operands -> acc m=lane&15, n=quad*4+reg -> float4 epilogue.
#define GLDS(g, l) __builtin_amdgcn_global_load_lds(                        \
        (const __attribute__((address_space(1))) void*)(g),                 \
        (__attribute__((address_space(3))) void*)(l), 16, 0, 0)

template <int AMODE, bool OUT_BF16>
__global__ __launch_bounds__(512, 4) void gemm_kernel(
        const void* __restrict__ Aptr, const ushort* __restrict__ Bw,
        const float* __restrict__ bias, void* __restrict__ Cout,
        const float* __restrict__ Zin, const float* __restrict__ alpha_param,
        int M, int N, int K)
{
    __shared__ __align__(16) ushort As[2][128 * 32];   //  8 KB each
    __shared__ __align__(16) ushort Bs[2][256 * 32];   // 16 KB each

    const int tid  = threadIdx.x;           // 0..511
    const int lane = tid & 63;
    const int wave = tid >> 6;              // 0..7
    const int wr = wave >> 2, wc = wave & 3;
    const int bm = blockIdx.y, bn = blockIdx.x;
    const int quad = lane >> 4, r16 = lane & 15;

    // staging map: thread -> A row = tid>>2 (0..127), k-off = (tid&3)*8
    const int srow = tid >> 2;
    const int skoff = (tid & 3) * 8;
    const float*  Ag32 = (const float*) Aptr + (size_t)(bm * 128 + srow) * K + skoff;
    const ushort* Ag16 = (const ushort*)Aptr + (size_t)(bm * 128 + srow) * K + skoff;
    // B rows: chunk c in {0,1}: row = c*128 + srow
    const ushort* Bg0 = Bw + (size_t)(bn * 256 + srow) * K + skoff;
    const ushort* Bg1 = Bg0 + (size_t)128 * K;

    // AMODE 2: per-thread row is fixed -> fixed (b, chunk, tau).
    // Precompute per-head decay factors c_h^{tau+1} as NAMED scalars (a
    // runtime-indexed array would go to scratch -- select-chain instead).
    float fc0=0.f,fc1=0.f,fc2=0.f,fc3=0.f,fc4=0.f,fc5=0.f,fc6=0.f,fc7=0.f;
    const float* Zc = nullptr;
    if (AMODE == 2) {
        const int m   = bm * 128 + srow;
        const int tau = m & (CHUNK - 1);         // t % 64 (64 | 8192)
        const int bb  = m >> 13;                 // batch index
        const int tch = (m & (SEQ - 1)) >> 6;    // chunk index
        Zc = Zin + (size_t)tch * NCHAN + (size_t)bb * DIM;
        const float t1 = (float)(tau + 1);
        float a, c;
        a = 1.f/(1.f+expf(-alpha_param[0])); c = 1.f - a; fc0 = exp2f(t1 * log2f(c));
        a = 1.f/(1.f+expf(-alpha_param[1])); c = 1.f - a; fc1 = exp2f(t1 * log2f(c));
        a = 1.f/(1.f+expf(-alpha_param[2])); c = 1.f - a; fc2 = exp2f(t1 * log2f(c));
        a = 1.f/(1.f+expf(-alpha_param[3])); c = 1.f - a; fc3 = exp2f(t1 * log2f(c));
        a = 1.f/(1.f+expf(-alpha_param[4])); c = 1.f - a; fc4 = exp2f(t1 * log2f(c));
        a = 1.f/(1.f+expf(-alpha_param[5])); c = 1.f - a; fc5 = exp2f(t1 * log2f(c));
        a = 1.f/(1.f+expf(-alpha_param[6])); c = 1.f - a; fc6 = exp2f(t1 * log2f(c));
        a = 1.f/(1.f+expf(-alpha_param[7])); c = 1.f - a; fc7 = exp2f(t1 * log2f(c));
    }
    auto selfac = [&](int hh) -> float {
        float f = fc0;
        f = (hh == 1) ? fc1 : f;
        f = (hh == 2) ? fc2 : f;
        f = (hh == 3) ? fc3 : f;
        f = (hh == 4) ? fc4 : f;
        f = (hh == 5) ? fc5 : f;
        f = (hh == 6) ? fc6 : f;
        f = (hh == 7) ? fc7 : f;
        return f;
    };
    auto stageA2 = [&](int ko, int b) {     // immediate load+fix+write (prologue)
        usx8 av = *(const usx8*)(Ag16 + ko);
        const int dbase = ko + skoff;
        float4 zv0 = *(const float4*)&Zc[dbase];
        float4 zv1 = *(const float4*)&Zc[dbase + 4];
        float fac = selfac(dbase >> 6);
        usx8 w;
        w[0] = f2bf(bf2f(av[0]) + fac * zv0.x);
        w[1] = f2bf(bf2f(av[1]) + fac * zv0.y);
        w[2] = f2bf(bf2f(av[2]) + fac * zv0.z);
        w[3] = f2bf(bf2f(av[3]) + fac * zv0.w);
        w[4] = f2bf(bf2f(av[4]) + fac * zv1.x);
        w[5] = f2bf(bf2f(av[5]) + fac * zv1.y);
        w[6] = f2bf(bf2f(av[6]) + fac * zv1.z);
        w[7] = f2bf(bf2f(av[7]) + fac * zv1.w);
        *(usx8*)&As[b][tid * 8] = w;
    };

    f32x4 acc[4][4];
    #pragma unroll
    for (int i = 0; i < 4; i++)
        #pragma unroll
        for (int j = 0; j < 4; j++)
            acc[i][j] = f32x4{0.f, 0.f, 0.f, 0.f};

    const int nIter = K / 32;

    auto stageB = [&](int k0, int b) {
        GLDS(Bg0 + k0, &Bs[b][tid * 8]);
        GLDS(Bg1 + k0, &Bs[b][128 * 32 + tid * 8]);
    };
    auto stageA16 = [&](int k0, int b) {
        GLDS(Ag16 + k0, &As[b][tid * 8]);
    };

    // prologue
    stageB(0, 0);
    if (AMODE == 1) {
        float a0[8];
        #pragma unroll
        for (int u = 0; u < 8; u++) a0[u] = Ag32[u];
        usx8 w;
        #pragma unroll
        for (int u = 0; u < 8; u++) w[u] = f2bf(a0[u]);
        *(usx8*)&As[0][tid * 8] = w;
    } else if (AMODE == 2) {
        stageA2(0, 0);
    } else {
        stageA16(0, 0);
    }

    int buf = 0;
    for (int k = 0; k < nIter; ++k) {
        __syncthreads();   // buf ready (vm+lgkm drained); buf^1 reads done

        float anext[8];
        usx8 av_n; float4 zn0, zn1; float fac_n = 0.f;
        const bool more = (k + 1 < nIter);
        if (more) {
            const int ko = (k + 1) * 32;
            stageB(ko, buf ^ 1);
            if (AMODE == 1) {
                #pragma unroll
                for (int u = 0; u < 8; u++) anext[u] = Ag32[ko + u];
            } else if (AMODE == 2) {
                av_n = *(const usx8*)(Ag16 + ko);
                const int dbase = ko + skoff;
                zn0 = *(const float4*)&Zc[dbase];
                zn1 = *(const float4*)&Zc[dbase + 4];
                fac_n = selfac(dbase >> 6);
            } else {
                stageA16(ko, buf ^ 1);
            }
        }

        bf16x8 af[4], bfr[4];
        #pragma unroll
        for (int i = 0; i < 4; i++)
            af[i] = *(const bf16x8*)&As[buf][(wr * 64 + i * 16 + r16) * 32 + quad * 8];
        #pragma unroll
        for (int j = 0; j < 4; j++)
            bfr[j] = *(const bf16x8*)&Bs[buf][(wc * 64 + j * 16 + r16) * 32 + quad * 8];

        #pragma unroll
        for (int i = 0; i < 4; i++)
            #pragma unroll
            for (int j = 0; j < 4; j++)
                acc[i][j] = __builtin_amdgcn_mfma_f32_16x16x32_bf16(
                                bfr[j], af[i], acc[i][j], 0, 0, 0);  // swapped

        if (more) {
            if (AMODE == 1) {
                usx8 w;
                #pragma unroll
                for (int u = 0; u < 8; u++) w[u] = f2bf(anext[u]);
                *(usx8*)&As[buf ^ 1][tid * 8] = w;
            } else if (AMODE == 2) {
                usx8 w;
                w[0] = f2bf(bf2f(av_n[0]) + fac_n * zn0.x);
                w[1] = f2bf(bf2f(av_n[1]) + fac_n * zn0.y);
                w[2] = f2bf(bf2f(av_n[2]) + fac_n * zn0.z);
                w[3] = f2bf(bf2f(av_n[3]) + fac_n * zn0.w);
                w[4] = f2bf(bf2f(av_n[4]) + fac_n * zn1.x);
                w[5] = f2bf(bf2f(av_n[5]) + fac_n * zn1.y);
                w[6] = f2bf(bf2f(av_n[6]) + fac_n * zn1.z);
                w[7] = f2bf(bf2f(av_n[7]) + fac_n * zn1.w);
                *(usx8*)&As[buf ^ 1][tid * 8] = w;
            }
        }
        buf ^= 1;
    }

    // epilogue: m = lane&15 (per i-tile), n = quad*4 + reg
    #pragma unroll
    for (int i = 0; i < 4; i++) {
        const int m = bm * 128 + wr * 64 + i * 16 + r16;
        #pragma unroll
        for (int j = 0; j < 4; j++) {
            const int n0 = bn * 256 + wc * 64 + j * 16 + quad * 4;
            const float4 bv = *(const float4*)&bias[n0];
            float v0 = acc[i][j][0] + bv.x;
            float v1 = acc[i][j][1] + bv.y;
            float v2 = acc[i][j][2] + bv.z;
            float v3 = acc[i][j][3] + bv.w;
            size_t idx = (size_t)m * N + n0;
            if (OUT_BF16) {
                ushort4 r;
                r.x = f2bf(v0); r.y = f2bf(v1); r.z = f2bf(v2); r.w = f2bf(v3);
                *(ushort4*)&((ushort*)Cout)[idx] = r;
            } else {
                *(float4*)&((float*)Cout)[idx] = make_float4(v0, v1, v2, v3);
            }
        }
    }
}

// ---------------- chunk-local scan (single xp read) ----------------
// z_local[t] = c*z_local[t-1] + alpha*(xp[t]-xp[t-1]), zero carry-in,
// TRUE prev (xp[t0-1], or init_state at chunk 0). Writes z_local (bf16)
// and the chunk tail L -> Lfin[chunk][ch]. The cross-chunk carry is
// applied later inside GEMM2's A-staging (superposition of the linear
// recurrence): z[t] = z_local[t] + c^{tau+1} * Z[chunk].
__global__ void scan_local_kernel(const ushort* __restrict__ xp,
                                  const float* __restrict__ alpha_param,
                                  const float* __restrict__ init_state,
                                  float* __restrict__ Lfin,    // [NCHUNK][NCHAN]
                                  ushort* __restrict__ zout)
{
    const int tid   = threadIdx.x;         // 0..255
    const int chunk = blockIdx.x;          // 0..NCHUNK-1
    const int b     = blockIdx.y;          // 0..3
    const int d0    = tid * 2;             // 0..510 ; d = h*64+dh
    const int h     = d0 >> 6;

    const float alpha = 1.0f / (1.0f + expf(-alpha_param[h]));
    const float cdec  = 1.0f - alpha;
    const int   t0    = chunk * CHUNK;
    const size_t baseRow = (size_t)b * SEQ;
    const int ch0 = b * DIM + d0;

    float prev0, prev1;
    if (chunk == 0) {
        prev0 = init_state[d0]; prev1 = init_state[d0 + 1];
    } else {
        uint u = *(const uint*)&xp[(baseRow + t0 - 1) * DIM + d0];
        prev0 = bf2f((ushort)(u & 0xffffu)); prev1 = bf2f((ushort)(u >> 16));
    }
    float z0 = 0.f, z1 = 0.f;
    const ushort* p = xp   + (baseRow + t0) * DIM + d0;
    ushort*       q = zout + (baseRow + t0) * DIM + d0;
    #pragma unroll 8
    for (int t = 0; t < CHUNK; ++t) {
        uint u = *(const uint*)&p[(size_t)t * DIM];
        float cur0 = bf2f((ushort)(u & 0xffffu));
        float cur1 = bf2f((ushort)(u >> 16));
        z0 = cdec * z0 + alpha * (cur0 - prev0);
        z1 = cdec * z1 + alpha * (cur1 - prev1);
        prev0 = cur0; prev1 = cur1;
        uint w = (uint)f2bf(z0) | ((uint)f2bf(z1) << 16);
        *(uint*)&q[(size_t)t * DIM] = w;
    }
    *(float2*)&Lfin[(size_t)chunk * NCHAN + ch0] = make_float2(z0, z1);
}

// Per-channel carry scan across chunks, chunk-major layout, 16-deep
// register prefetch (independent loads batched -> ~8 latency exposures
// instead of 128).  Z[chunk] = carry-in state (true z at chunk start - 1).
__global__ void scan_fix2_kernel(const float* __restrict__ Lfin,
                                 const float* __restrict__ alpha_param,
                                 const float* __restrict__ init_state,
                                 float* __restrict__ Zin)     // [NCHUNK][NCHAN]
{
    int ch = blockIdx.x * blockDim.x + threadIdx.x;   // 0..2047 = b*512+d
    if (ch >= NCHAN) return;
    int d = ch & (DIM - 1);
    int h = d >> 6;
    float alpha = 1.0f / (1.0f + expf(-alpha_param[h]));
    float c = 1.0f - alpha;
    float cT = c;
    #pragma unroll
    for (int i = 0; i < 6; i++) cT *= cT;             // c^64, exact squarings
    float Z = init_state[d];                          // z[-1] = init_state
    const float* Lp = Lfin + ch;
    float*       Zp = Zin  + ch;
    constexpr int PF = 16;
    float Lr[PF];
    #pragma unroll
    for (int j = 0; j < PF; ++j) Lr[j] = Lp[(size_t)j * NCHAN];
    for (int g = 0; g < NCHUNK / PF; ++g) {           // 8 groups
        #pragma unroll
        for (int j = 0; j < PF; ++j) {
            float Lc = Lr[j];
            if (g + 1 < NCHUNK / PF)
                Lr[j] = Lp[(size_t)((g + 1) * PF + j) * NCHAN];
            Zp[(size_t)(g * PF + j) * NCHAN] = Z;
            Z = Lc + cT * Z;
        }
    }
}

extern "C" void kernel_launch(void* const* d_in, const int* in_sizes, int n_in,
                              void* d_out, int out_size, void* d_ws, size_t ws_size,
                              hipStream_t stream) {
    const float* x           = (const float*)d_in[0];
    const float* W_in        = (const float*)d_in[1];
    const float* b_in        = (const float*)d_in[2];
    const float* W_out       = (const float*)d_in[3];
    const float* b_out       = (const float*)d_in[4];
    const float* init_state  = (const float*)d_in[5];
    const float* alpha_param = (const float*)d_in[6];
    float* out = (float*)d_out;

    // workspace layout (ushort units)
    ushort* z_bf    = (ushort*)d_ws;                        // 16,777,216
    ushort* win_bf  = z_bf   + (size_t)MROWS * DIM;         //    262,144
    ushort* wout_bf = win_bf + (size_t)DIM * DIM;           //    262,144
    ushort* xp_bf   = wout_bf + (size_t)DIM * DIM;          // 16,777,216
    float*  Lfin    = (float*)(xp_bf + (size_t)MROWS * DIM);
    float*  Zin     = Lfin + (size_t)NCHAN * NCHUNK;

    const int nw4 = (DIM * DIM) / 4;          //    65,536
    weights_to_bf16_kernel<<<(2 * nw4 + 255) / 256, 256, 0, stream>>>(
        W_in, W_out, win_bf, nw4);

    dim3 ggrid(DIM / 256, MROWS / 128);       // (2, 256)
    // GEMM1: A = x (fp32, converted in-staging), out = xp (bf16)
    gemm_kernel<1, true><<<ggrid, 512, 0, stream>>>(
        (const void*)x, win_bf, b_in, (void*)xp_bf,
        nullptr, nullptr, MROWS, DIM, DIM);

    // chunk-local scan: xp read once, z_local + L written
    dim3 sgrid(NCHUNK, BATCH);                // (128, 4)
    scan_local_kernel<<<sgrid, 256, 0, stream>>>(
        xp_bf, alpha_param, init_state, Lfin, z_bf);
    scan_fix2_kernel<<<NCHAN / 256, 256, 0, stream>>>(
        Lfin, alpha_param, init_state, Zin);

    // GEMM2: A = z_local (bf16) + carry correction fused in staging, out fp32
    gemm_kernel<2, false><<<ggrid, 512, 0, stream>>>(
        (const void*)z_bf, wout_bf, b_out, (void*)out,
        Zin, alpha_param, MROWS, DIM, DIM);
}

// Round 3
// 201.965 us; speedup vs baseline: 1.0537x; 1.0323x over previous
//
#include <hip/hip_runtime.h>
#include <stdint.h>

// Problem constants (from reference): B=4, N=8192, D=512, H=8, Dh=64
#define SEQ      8192
#define BATCH    4
#define DIM      512
#define MROWS    32768      // BATCH*SEQ
#define CHUNK    64
#define NCHUNK   128        // SEQ / CHUNK (per batch); 512 global chunks
#define NCHAN    2048       // BATCH * DIM
#define NHEAD    8
#define NGCHUNK  512        // BATCH * NCHUNK
#define XLD      264        // X tile row stride (256 + 8 pad)

typedef unsigned short ushort;
typedef unsigned int   uint;
typedef __bf16 bf16x8 __attribute__((ext_vector_type(8)));
typedef float  f32x4  __attribute__((ext_vector_type(4)));
typedef ushort usx8   __attribute__((ext_vector_type(8)));

__device__ __forceinline__ ushort f2bf(float f) {
    unsigned u = __float_as_uint(f);
    unsigned r = (u + 0x7fffu + ((u >> 16) & 1u)) >> 16;   // RNE
    return (ushort)r;
}
__device__ __forceinline__ float bf2f(ushort v) {
    return __uint_as_float(((unsigned)v) << 16);
}

// =====================================================================
// GEMM1 + fused chunk-local scan + W_out converter (blockIdx.y == 0)
//   xp = x @ W_in^T + b_in  (computed in-register, tile kept in LDS)
//   z_loc'[t] = c*z' + alpha*(xp[t]-xp[t-1]), prev=0 at chunk start
//   writes: z_loc' (bf16), L' = chunk tail (f32), XpT[g+1] = xp tail (f32)
//   Cross-chunk carry applied later in GEMM2: z = z_loc' + c^tau * G.
// A (x, fp32) and B (W_in, fp32) both reg-staged with fused cvt->bf16.
// 128x256 tile, 8 waves (2m x 4n), dbuf LDS, 1 barrier/iter.
// =====================================================================
__global__ __launch_bounds__(512, 4) void gemm1_scan_kernel(
        const float* __restrict__ x,    const float* __restrict__ W_in,
        const float* __restrict__ b_in, const float* __restrict__ W_out,
        const float* __restrict__ alpha_param,
        ushort* __restrict__ zout,      ushort* __restrict__ wout_bf,
        float* __restrict__ Lfin,       float* __restrict__ XpT)
{
    const int tid = threadIdx.x;            // 0..511
    const int bn  = blockIdx.x;             // 0..1

    // ---- converter blocks: fp32 W_out -> bf16 (runs first in dispatch order)
    if (blockIdx.y == 0) {
        const float4* src = (const float4*)W_out;
        const int n4 = (DIM * DIM) / 4;     // 65536
        for (int idx = bn * 512 + tid; idx < n4; idx += 1024) {
            float4 v = src[idx];
            ushort4 r;
            r.x = f2bf(v.x); r.y = f2bf(v.y); r.z = f2bf(v.z); r.w = f2bf(v.w);
            ((ushort4*)wout_bf)[idx] = r;
        }
        return;
    }
    const int bm = blockIdx.y - 1;          // 0..255

    // LDS: staging buffers (48 KB) overlaid with xp tile X[128][264] (66 KB)
    __shared__ __align__(16) char smem[2 * XLD * 128];   // 67584 B
    ushort* As0 = (ushort*)smem;                 // [2][128*32]  16 KB
    ushort* Bs0 = (ushort*)(smem + 16384);       // [2][256*32]  32 KB
    ushort* X   = (ushort*)smem;                 // [128][XLD]   66 KB (epilogue)

    const int lane = tid & 63;
    const int wave = tid >> 6;
    const int wr = wave >> 2, wc = wave & 3;
    const int quad = lane >> 4, r16 = lane & 15;

    // staging map: thread -> row = tid>>2 (0..127), k-off = (tid&3)*8
    const int srow  = tid >> 2;
    const int skoff = (tid & 3) * 8;
    const float* Ag  = x    + (size_t)(bm * 128 + srow) * DIM + skoff;
    const float* Bg0 = W_in + (size_t)(bn * 256 + srow) * DIM + skoff;
    const float* Bg1 = Bg0  + (size_t)128 * DIM;

    f32x4 acc[4][4];
    #pragma unroll
    for (int i = 0; i < 4; i++)
        #pragma unroll
        for (int j = 0; j < 4; j++)
            acc[i][j] = f32x4{0.f, 0.f, 0.f, 0.f};

    const int nIter = DIM / 32;             // 16

    auto cvt8 = [&](const float* s) {
        usx8 w;
        #pragma unroll
        for (int u = 0; u < 8; u++) w[u] = f2bf(s[u]);
        return w;
    };

    // prologue: stage iter 0 into buf 0
    {
        float a[8], b0[8], b1[8];
        #pragma unroll
        for (int u = 0; u < 8; u++) { a[u] = Ag[u]; b0[u] = Bg0[u]; b1[u] = Bg1[u]; }
        *(usx8*)&As0[tid * 8]        = cvt8(a);
        *(usx8*)&Bs0[tid * 8]        = cvt8(b0);
        *(usx8*)&Bs0[4096 + tid * 8] = cvt8(b1);
    }

    int buf = 0;
    for (int k = 0; k < nIter; ++k) {
        __syncthreads();   // buf staged (lgkm drained); buf^1 reads done

        float an[8], bn0[8], bn1[8];
        const bool more = (k + 1 < nIter);
        if (more) {
            const int ko = (k + 1) * 32;
            #pragma unroll
            for (int u = 0; u < 8; u++) {
                an[u]  = Ag[ko + u];
                bn0[u] = Bg0[ko + u];
                bn1[u] = Bg1[ko + u];
            }
        }

        bf16x8 af[4], bfr[4];
        #pragma unroll
        for (int i = 0; i < 4; i++)
            af[i] = *(const bf16x8*)&As0[buf * 4096 + (wr * 64 + i * 16 + r16) * 32 + quad * 8];
        #pragma unroll
        for (int j = 0; j < 4; j++)
            bfr[j] = *(const bf16x8*)&Bs0[buf * 8192 + (wc * 64 + j * 16 + r16) * 32 + quad * 8];

        #pragma unroll
        for (int i = 0; i < 4; i++)
            #pragma unroll
            for (int j = 0; j < 4; j++)
                acc[i][j] = __builtin_amdgcn_mfma_f32_16x16x32_bf16(
                                bfr[j], af[i], acc[i][j], 0, 0, 0);  // swapped

        if (more) {
            const int nb = buf ^ 1;
            *(usx8*)&As0[nb * 4096 + tid * 8]        = cvt8(an);
            *(usx8*)&Bs0[nb * 8192 + tid * 8]        = cvt8(bn0);
            *(usx8*)&Bs0[nb * 8192 + 4096 + tid * 8] = cvt8(bn1);
        }
        buf ^= 1;
    }

    // ---- epilogue part 1: xp tile (C + bias) -> LDS X[128][XLD] (bf16)
    __syncthreads();   // all waves done reading As/Bs before overwrite
    #pragma unroll
    for (int i = 0; i < 4; i++) {
        const int ml = wr * 64 + i * 16 + r16;
        #pragma unroll
        for (int j = 0; j < 4; j++) {
            const int nl = wc * 64 + j * 16 + quad * 4;
            const float4 bv = *(const float4*)&b_in[bn * 256 + nl];
            ushort4 r4;
            r4.x = f2bf(acc[i][j][0] + bv.x);
            r4.y = f2bf(acc[i][j][1] + bv.y);
            r4.z = f2bf(acc[i][j][2] + bv.z);
            r4.w = f2bf(acc[i][j][3] + bv.w);
            *(ushort4*)&X[ml * XLD + nl] = r4;
        }
    }
    __syncthreads();

    // ---- epilogue part 2: chunk-local scan (prev = 0 at chunk start)
    // thread -> (chalf, cidx): chunk g = 2*bm + chalf, channel d = bn*256+cidx
    const int chalf = tid >> 8;             // 0..1
    const int cidx  = tid & 255;            // 0..255
    const int g     = 2 * bm + chalf;       // global chunk 0..511
    const int d     = bn * 256 + cidx;      // 0..511
    const int h     = d >> 6;
    const float alpha = 1.0f / (1.0f + expf(-alpha_param[h]));
    const float c     = 1.0f - alpha;

    const ushort* Xr  = X + chalf * 64 * XLD + cidx;
    ushort* zrow = zout + ((size_t)(bm * 128 + chalf * 64)) * DIM + d;

    float z = 0.f, prev = 0.f;
    #pragma unroll 8
    for (int r = 0; r < CHUNK; ++r) {
        float xv = bf2f(Xr[r * XLD]);
        z = c * z + alpha * (xv - prev);
        prev = xv;
        zrow[(size_t)r * DIM] = f2bf(z);
    }
    Lfin[(size_t)g * 512 + d]       = z;     // L' tail
    XpT[(size_t)(g + 1) * 512 + d]  = prev;  // xp tail -> next chunk's xpt
}

// =====================================================================
// Carry chain:  G_k = c*Z_k - alpha*xpt_k ;  Z_{k+1} = L'_k + c^63 * G_k
// xpt_0 = init_state (chunk 0 of each batch), Z_0 = init_state.
// 16-deep register prefetch of L' and XpT (chunk-major layout).
// =====================================================================
__global__ void scan_fixg_kernel(const float* __restrict__ Lfin,
                                 const float* __restrict__ XpT,
                                 const float* __restrict__ alpha_param,
                                 const float* __restrict__ init_state,
                                 float* __restrict__ G)
{
    int ch = blockIdx.x * blockDim.x + threadIdx.x;   // 0..2047
    if (ch >= NCHAN) return;
    const int b = ch >> 9;
    const int d = ch & (DIM - 1);
    const int h = d >> 6;
    const float alpha = 1.0f / (1.0f + expf(-alpha_param[h]));
    const float c = 1.0f - alpha;
    const float c2 = c * c, c4 = c2 * c2, c8 = c4 * c4,
                c16 = c8 * c8, c32 = c16 * c16;
    const float c63 = c32 * c16 * c8 * c4 * c2 * c;
    const float sinit = init_state[d];

    float Z = sinit;
    const float* Lp = Lfin + (size_t)(b * NCHUNK) * 512 + d;
    const float* Xp = XpT  + (size_t)(b * NCHUNK) * 512 + d;
    float*       Gp = G    + (size_t)(b * NCHUNK) * 512 + d;

    constexpr int PF = 16;
    float Lr[PF], Xr[PF];
    #pragma unroll
    for (int j = 0; j < PF; ++j) {
        Lr[j] = Lp[(size_t)j * 512];
        Xr[j] = Xp[(size_t)j * 512];
    }
    for (int gr = 0; gr < NCHUNK / PF; ++gr) {        // 8 groups
        #pragma unroll
        for (int j = 0; j < PF; ++j) {
            const int kl = gr * PF + j;
            const float xpt = (kl == 0) ? sinit : Xr[j];
            const float Lc  = Lr[j];
            if (gr + 1 < NCHUNK / PF) {
                Lr[j] = Lp[(size_t)((gr + 1) * PF + j) * 512];
                Xr[j] = Xp[(size_t)((gr + 1) * PF + j) * 512];
            }
            const float Gv = c * Z - alpha * xpt;
            Gp[(size_t)kl * 512] = Gv;
            Z = Lc + c63 * Gv;
        }
    }
}

// =====================================================================
// GEMM2: out = z @ W_out^T + b_out ; carry correction fused in A-staging:
//   a[tau, d] += c_h^tau * G[g][d]   (g = row>>6, tau = row&63)
// A reg-staged bf16 + fix, B via global_load_lds (wout_bf, L2-resident).
// =====================================================================
#define GLDS(g, l) __builtin_amdgcn_global_load_lds(                        \
        (const __attribute__((address_space(1))) void*)(g),                 \
        (__attribute__((address_space(3))) void*)(l), 16, 0, 0)

__global__ __launch_bounds__(512, 4) void gemm2_kernel(
        const ushort* __restrict__ Az, const ushort* __restrict__ Bw,
        const float* __restrict__ bias, float* __restrict__ Cout,
        const float* __restrict__ G, const float* __restrict__ alpha_param)
{
    __shared__ __align__(16) ushort As[2][128 * 32];   //  8 KB each
    __shared__ __align__(16) ushort Bs[2][256 * 32];   // 16 KB each

    const int tid  = threadIdx.x;
    const int lane = tid & 63;
    const int wave = tid >> 6;
    const int wr = wave >> 2, wc = wave & 3;
    const int bm = blockIdx.y, bn = blockIdx.x;
    const int quad = lane >> 4, r16 = lane & 15;

    const int srow  = tid >> 2;
    const int skoff = (tid & 3) * 8;
    const ushort* Ag16 = Az + (size_t)(bm * 128 + srow) * DIM + skoff;
    const ushort* Bg0  = Bw + (size_t)(bn * 256 + srow) * DIM + skoff;
    const ushort* Bg1  = Bg0 + (size_t)128 * DIM;

    // per-thread fixed row -> fixed (g, tau); factors c_h^tau as named scalars
    const int m   = bm * 128 + srow;
    const int tau = m & (CHUNK - 1);
    const float* Gc = G + (size_t)(m >> 6) * 512;
    const float t1 = (float)tau;
    float fc0,fc1,fc2,fc3,fc4,fc5,fc6,fc7;
    {
        float a, c;
        a = 1.f/(1.f+expf(-alpha_param[0])); c = 1.f - a; fc0 = exp2f(t1 * log2f(c));
        a = 1.f/(1.f+expf(-alpha_param[1])); c = 1.f - a; fc1 = exp2f(t1 * log2f(c));
        a = 1.f/(1.f+expf(-alpha_param[2])); c = 1.f - a; fc2 = exp2f(t1 * log2f(c));
        a = 1.f/(1.f+expf(-alpha_param[3])); c = 1.f - a; fc3 = exp2f(t1 * log2f(c));
        a = 1.f/(1.f+expf(-alpha_param[4])); c = 1.f - a; fc4 = exp2f(t1 * log2f(c));
        a = 1.f/(1.f+expf(-alpha_param[5])); c = 1.f - a; fc5 = exp2f(t1 * log2f(c));
        a = 1.f/(1.f+expf(-alpha_param[6])); c = 1.f - a; fc6 = exp2f(t1 * log2f(c));
        a = 1.f/(1.f+expf(-alpha_param[7])); c = 1.f - a; fc7 = exp2f(t1 * log2f(c));
    }
    auto selfac = [&](int hh) -> float {
        float f = fc0;
        f = (hh == 1) ? fc1 : f;
        f = (hh == 2) ? fc2 : f;
        f = (hh == 3) ? fc3 : f;
        f = (hh == 4) ? fc4 : f;
        f = (hh == 5) ? fc5 : f;
        f = (hh == 6) ? fc6 : f;
        f = (hh == 7) ? fc7 : f;
        return f;
    };
    auto fixpack = [&](usx8 av, float4 z0, float4 z1, float fac) {
        usx8 w;
        w[0] = f2bf(bf2f(av[0]) + fac * z0.x);
        w[1] = f2bf(bf2f(av[1]) + fac * z0.y);
        w[2] = f2bf(bf2f(av[2]) + fac * z0.z);
        w[3] = f2bf(bf2f(av[3]) + fac * z0.w);
        w[4] = f2bf(bf2f(av[4]) + fac * z1.x);
        w[5] = f2bf(bf2f(av[5]) + fac * z1.y);
        w[6] = f2bf(bf2f(av[6]) + fac * z1.z);
        w[7] = f2bf(bf2f(av[7]) + fac * z1.w);
        return w;
    };

    f32x4 acc[4][4];
    #pragma unroll
    for (int i = 0; i < 4; i++)
        #pragma unroll
        for (int j = 0; j < 4; j++)
            acc[i][j] = f32x4{0.f, 0.f, 0.f, 0.f};

    const int nIter = DIM / 32;

    auto stageB = [&](int k0, int b) {
        GLDS(Bg0 + k0, &Bs[b][tid * 8]);
        GLDS(Bg1 + k0, &Bs[b][128 * 32 + tid * 8]);
    };

    // prologue
    stageB(0, 0);
    {
        usx8 av = *(const usx8*)(Ag16);
        float4 z0 = *(const float4*)&Gc[skoff];
        float4 z1 = *(const float4*)&Gc[skoff + 4];
        *(usx8*)&As[0][tid * 8] = fixpack(av, z0, z1, selfac(skoff >> 6));
    }

    int buf = 0;
    for (int k = 0; k < nIter; ++k) {
        __syncthreads();

        usx8 av_n; float4 zn0, zn1; float fac_n = 0.f;
        const bool more = (k + 1 < nIter);
        if (more) {
            const int ko = (k + 1) * 32;
            stageB(ko, buf ^ 1);
            av_n = *(const usx8*)(Ag16 + ko);
            const int dbase = ko + skoff;
            zn0 = *(const float4*)&Gc[dbase];
            zn1 = *(const float4*)&Gc[dbase + 4];
            fac_n = selfac(dbase >> 6);
        }

        bf16x8 af[4], bfr[4];
        #pragma unroll
        for (int i = 0; i < 4; i++)
            af[i] = *(const bf16x8*)&As[buf][(wr * 64 + i * 16 + r16) * 32 + quad * 8];
        #pragma unroll
        for (int j = 0; j < 4; j++)
            bfr[j] = *(const bf16x8*)&Bs[buf][(wc * 64 + j * 16 + r16) * 32 + quad * 8];

        #pragma unroll
        for (int i = 0; i < 4; i++)
            #pragma unroll
            for (int j = 0; j < 4; j++)
                acc[i][j] = __builtin_amdgcn_mfma_f32_16x16x32_bf16(
                                bfr[j], af[i], acc[i][j], 0, 0, 0);  // swapped

        if (more)
            *(usx8*)&As[buf ^ 1][tid * 8] = fixpack(av_n, zn0, zn1, fac_n);
        buf ^= 1;
    }

    // epilogue: m = lane&15 (per i-tile), n = quad*4 + reg
    #pragma unroll
    for (int i = 0; i < 4; i++) {
        const int mr = bm * 128 + wr * 64 + i * 16 + r16;
        #pragma unroll
        for (int j = 0; j < 4; j++) {
            const int n0 = bn * 256 + wc * 64 + j * 16 + quad * 4;
            const float4 bv = *(const float4*)&bias[n0];
            float4 v = make_float4(acc[i][j][0] + bv.x, acc[i][j][1] + bv.y,
                                   acc[i][j][2] + bv.z, acc[i][j][3] + bv.w);
            *(float4*)&Cout[(size_t)mr * DIM + n0] = v;
        }
    }
}

extern "C" void kernel_launch(void* const* d_in, const int* in_sizes, int n_in,
                              void* d_out, int out_size, void* d_ws, size_t ws_size,
                              hipStream_t stream) {
    const float* x           = (const float*)d_in[0];
    const float* W_in        = (const float*)d_in[1];
    const float* b_in        = (const float*)d_in[2];
    const float* W_out       = (const float*)d_in[3];
    const float* b_out       = (const float*)d_in[4];
    const float* init_state  = (const float*)d_in[5];
    const float* alpha_param = (const float*)d_in[6];
    float* out = (float*)d_out;

    // workspace layout
    ushort* z_bf    = (ushort*)d_ws;                       // 32 MB
    ushort* wout_bf = z_bf + (size_t)MROWS * DIM;          // 0.5 MB
    float*  Lfin    = (float*)(wout_bf + (size_t)DIM * DIM);        // [512][512]
    float*  XpT     = Lfin + (size_t)NGCHUNK * 512;                 // [513][512]
    float*  G       = XpT  + (size_t)(NGCHUNK + 1) * 512;           // [512][512]

    // GEMM1 + fused scan; blockIdx.y==0 converts W_out
    dim3 g1(2, MROWS / 128 + 1);              // (2, 257)
    gemm1_scan_kernel<<<g1, 512, 0, stream>>>(
        x, W_in, b_in, W_out, alpha_param, z_bf, wout_bf, Lfin, XpT);

    // cross-chunk carry -> G
    scan_fixg_kernel<<<NCHAN / 256, 256, 0, stream>>>(
        Lfin, XpT, alpha_param, init_state, G);

    // GEMM2 with fused carry application
    dim3 g2(2, MROWS / 128);                  // (2, 256)
    gemm2_kernel<<<g2, 512, 0, stream>>>(
        z_bf, wout_bf, b_out, out, G, alpha_param);
}

// Round 4
// 196.476 us; speedup vs baseline: 1.0832x; 1.0279x over previous
//
#include <hip/hip_runtime.h>
#include <stdint.h>

// Problem constants (from reference): B=4, N=8192, D=512, H=8, Dh=64
#define SEQ      8192
#define BATCH    4
#define DIM      512
#define MROWS    32768      // BATCH*SEQ
#define CHUNK    64
#define NCHUNK   128        // SEQ / CHUNK (per batch); 512 global chunks
#define NCHAN    2048       // BATCH * DIM
#define NHEAD    8
#define NGCHUNK  512        // BATCH * NCHUNK
#define XLD      264        // X tile row stride (256 + 8 pad)

typedef unsigned short ushort;
typedef unsigned int   uint;
typedef __bf16 bf16x8 __attribute__((ext_vector_type(8)));
typedef float  f32x4  __attribute__((ext_vector_type(4)));
typedef ushort usx8   __attribute__((ext_vector_type(8)));

// native RNE f32->bf16 (hardware cvt; replaces 4-op integer RNE sequence)
__device__ __forceinline__ ushort f2bf(float f) {
    union { __bf16 h; ushort u; } cv;
    cv.h = (__bf16)f;
    return cv.u;
}
__device__ __forceinline__ float bf2f(ushort v) {
    return __uint_as_float(((unsigned)v) << 16);
}

// both weight matrices in one launch; outputs contiguous (win_bf then wout_bf)
__global__ void weights_to_bf16_kernel(const float* __restrict__ w_in,
                                       const float* __restrict__ w_out,
                                       ushort* __restrict__ dst, int n4each) {
    int i = blockIdx.x * blockDim.x + threadIdx.x;
    if (i >= 2 * n4each) return;
    const float4* src = (i < n4each) ? (const float4*)w_in
                                     : (const float4*)w_out - n4each;
    float4 v = src[i];
    ushort4 r;
    r.x = f2bf(v.x); r.y = f2bf(v.y); r.z = f2bf(v.z); r.w = f2bf(v.w);
    ((ushort4*)dst)[i] = r;
}

#define GLDS(g, l) __builtin_amdgcn_global_load_lds(                        \
        (const __attribute__((address_space(1))) void*)(g),                 \
        (__attribute__((address_space(3))) void*)(l), 16, 0, 0)

// =====================================================================
// GEMM1 + fused chunk-local scan
//   xp = x @ W_in^T + b_in  (tile kept in LDS, never written to global)
//   z_loc'[t] = c*z' + alpha*(xp[t]-xp[t-1]), prev=0 at chunk start
//   writes: z_loc' (bf16), L' = chunk tail (f32), XpT[g+1] = xp tail (f32)
//   Cross-chunk carry applied later in GEMM2: z = z_loc' + c^tau * G.
// A (x, fp32) reg-staged with fused cvt->bf16; B (W_in bf16, L2-resident)
// via global_load_lds (reg-staging B measured -21us in round 3).
// 128x256 tile, 8 waves (2m x 4n), dbuf LDS, 1 barrier/iter.
// =====================================================================
__global__ __launch_bounds__(512, 4) void gemm1_scan_kernel(
        const float* __restrict__ x,    const ushort* __restrict__ Bw,
        const float* __restrict__ b_in, const float* __restrict__ alpha_param,
        ushort* __restrict__ zout,
        float* __restrict__ Lfin,       float* __restrict__ XpT)
{
    // LDS: staging buffers (48 KB) overlaid with xp tile X[128][264] (66 KB)
    __shared__ __align__(16) char smem[2 * XLD * 128];   // 67584 B
    ushort* As0 = (ushort*)smem;                 // [2][128*32]  16 KB
    ushort* Bs0 = (ushort*)(smem + 16384);       // [2][256*32]  32 KB
    ushort* X   = (ushort*)smem;                 // [128][XLD]   66 KB (epilogue)

    const int tid = threadIdx.x;            // 0..511
    const int bn  = blockIdx.x;             // 0..1
    const int bm  = blockIdx.y;             // 0..255

    const int lane = tid & 63;
    const int wave = tid >> 6;
    const int wr = wave >> 2, wc = wave & 3;
    const int quad = lane >> 4, r16 = lane & 15;

    // staging map: thread -> row = tid>>2 (0..127), k-off = (tid&3)*8
    const int srow  = tid >> 2;
    const int skoff = (tid & 3) * 8;
    const float*  Ag  = x  + (size_t)(bm * 128 + srow) * DIM + skoff;
    const ushort* Bg0 = Bw + (size_t)(bn * 256 + srow) * DIM + skoff;
    const ushort* Bg1 = Bg0 + (size_t)128 * DIM;

    f32x4 acc[4][4];
    #pragma unroll
    for (int i = 0; i < 4; i++)
        #pragma unroll
        for (int j = 0; j < 4; j++)
            acc[i][j] = f32x4{0.f, 0.f, 0.f, 0.f};

    const int nIter = DIM / 32;             // 16

    auto stageB = [&](int k0, int b) {
        GLDS(Bg0 + k0, &Bs0[b * 8192 + tid * 8]);
        GLDS(Bg1 + k0, &Bs0[b * 8192 + 4096 + tid * 8]);
    };
    auto cvt8 = [&](const float* s) {
        usx8 w;
        #pragma unroll
        for (int u = 0; u < 8; u++) w[u] = f2bf(s[u]);
        return w;
    };

    // prologue: stage iter 0 into buf 0
    stageB(0, 0);
    {
        float a[8];
        #pragma unroll
        for (int u = 0; u < 8; u++) a[u] = Ag[u];
        *(usx8*)&As0[tid * 8] = cvt8(a);
    }

    int buf = 0;
    for (int k = 0; k < nIter; ++k) {
        __syncthreads();   // buf staged (vm+lgkm drained); buf^1 reads done

        float an[8];
        const bool more = (k + 1 < nIter);
        if (more) {
            const int ko = (k + 1) * 32;
            stageB(ko, buf ^ 1);
            #pragma unroll
            for (int u = 0; u < 8; u++) an[u] = Ag[ko + u];
        }

        bf16x8 af[4], bfr[4];
        #pragma unroll
        for (int i = 0; i < 4; i++)
            af[i] = *(const bf16x8*)&As0[buf * 4096 + (wr * 64 + i * 16 + r16) * 32 + quad * 8];
        #pragma unroll
        for (int j = 0; j < 4; j++)
            bfr[j] = *(const bf16x8*)&Bs0[buf * 8192 + (wc * 64 + j * 16 + r16) * 32 + quad * 8];

        #pragma unroll
        for (int i = 0; i < 4; i++)
            #pragma unroll
            for (int j = 0; j < 4; j++)
                acc[i][j] = __builtin_amdgcn_mfma_f32_16x16x32_bf16(
                                bfr[j], af[i], acc[i][j], 0, 0, 0);  // swapped

        if (more)
            *(usx8*)&As0[(buf ^ 1) * 4096 + tid * 8] = cvt8(an);
        buf ^= 1;
    }

    // ---- epilogue part 1: xp tile (C + bias) -> LDS X[128][XLD] (bf16)
    __syncthreads();   // all waves done reading As/Bs before overwrite
    #pragma unroll
    for (int i = 0; i < 4; i++) {
        const int ml = wr * 64 + i * 16 + r16;
        #pragma unroll
        for (int j = 0; j < 4; j++) {
            const int nl = wc * 64 + j * 16 + quad * 4;
            const float4 bv = *(const float4*)&b_in[bn * 256 + nl];
            ushort4 r4;
            r4.x = f2bf(acc[i][j][0] + bv.x);
            r4.y = f2bf(acc[i][j][1] + bv.y);
            r4.z = f2bf(acc[i][j][2] + bv.z);
            r4.w = f2bf(acc[i][j][3] + bv.w);
            *(ushort4*)&X[ml * XLD + nl] = r4;
        }
    }
    __syncthreads();

    // ---- epilogue part 2: chunk-local scan (prev = 0 at chunk start)
    // thread -> (chalf, cidx): chunk g = 2*bm + chalf, channel d = bn*256+cidx
    const int chalf = tid >> 8;             // 0..1
    const int cidx  = tid & 255;            // 0..255
    const int g     = 2 * bm + chalf;       // global chunk 0..511
    const int d     = bn * 256 + cidx;      // 0..511
    const int h     = d >> 6;
    const float alpha = 1.0f / (1.0f + expf(-alpha_param[h]));
    const float c     = 1.0f - alpha;

    const ushort* Xr  = X + chalf * 64 * XLD + cidx;
    ushort* zrow = zout + ((size_t)(bm * 128 + chalf * 64)) * DIM + d;

    float z = 0.f, prev = 0.f;
    #pragma unroll 8
    for (int r = 0; r < CHUNK; ++r) {
        float xv = bf2f(Xr[r * XLD]);
        z = c * z + alpha * (xv - prev);
        prev = xv;
        zrow[(size_t)r * DIM] = f2bf(z);
    }
    Lfin[(size_t)g * 512 + d]       = z;     // L' tail
    XpT[(size_t)(g + 1) * 512 + d]  = prev;  // xp tail -> next chunk's xpt
}

// =====================================================================
// Carry chain:  G_k = c*Z_k - alpha*xpt_k ;  Z_{k+1} = L'_k + c^63 * G_k
// xpt_0 = init_state (chunk 0 of each batch), Z_0 = init_state.
// 16-deep register prefetch of L' and XpT (chunk-major layout).
// =====================================================================
__global__ void scan_fixg_kernel(const float* __restrict__ Lfin,
                                 const float* __restrict__ XpT,
                                 const float* __restrict__ alpha_param,
                                 const float* __restrict__ init_state,
                                 float* __restrict__ G)
{
    int ch = blockIdx.x * blockDim.x + threadIdx.x;   // 0..2047
    if (ch >= NCHAN) return;
    const int b = ch >> 9;
    const int d = ch & (DIM - 1);
    const int h = d >> 6;
    const float alpha = 1.0f / (1.0f + expf(-alpha_param[h]));
    const float c = 1.0f - alpha;
    const float c2 = c * c, c4 = c2 * c2, c8 = c4 * c4,
                c16 = c8 * c8, c32 = c16 * c16;
    const float c63 = c32 * c16 * c8 * c4 * c2 * c;
    const float sinit = init_state[d];

    float Z = sinit;
    const float* Lp = Lfin + (size_t)(b * NCHUNK) * 512 + d;
    const float* Xp = XpT  + (size_t)(b * NCHUNK) * 512 + d;
    float*       Gp = G    + (size_t)(b * NCHUNK) * 512 + d;

    constexpr int PF = 16;
    float Lr[PF], Xr[PF];
    #pragma unroll
    for (int j = 0; j < PF; ++j) {
        Lr[j] = Lp[(size_t)j * 512];
        Xr[j] = Xp[(size_t)j * 512];
    }
    for (int gr = 0; gr < NCHUNK / PF; ++gr) {        // 8 groups
        #pragma unroll
        for (int j = 0; j < PF; ++j) {
            const int kl = gr * PF + j;
            const float xpt = (kl == 0) ? sinit : Xr[j];
            const float Lc  = Lr[j];
            if (gr + 1 < NCHUNK / PF) {
                Lr[j] = Lp[(size_t)((gr + 1) * PF + j) * 512];
                Xr[j] = Xp[(size_t)((gr + 1) * PF + j) * 512];
            }
            const float Gv = c * Z - alpha * xpt;
            Gp[(size_t)kl * 512] = Gv;
            Z = Lc + c63 * Gv;
        }
    }
}

// =====================================================================
// GEMM2: out = z @ W_out^T + b_out ; carry correction fused in A-staging:
//   a[tau, d] += c_h^tau * G[g][d]   (g = row>>6, tau = row&63)
// A reg-staged bf16 + fix, B via global_load_lds (wout_bf, L2-resident).
// =====================================================================
__global__ __launch_bounds__(512, 4) void gemm2_kernel(
        const ushort* __restrict__ Az, const ushort* __restrict__ Bw,
        const float* __restrict__ bias, float* __restrict__ Cout,
        const float* __restrict__ G, const float* __restrict__ alpha_param)
{
    __shared__ __align__(16) ushort As[2][128 * 32];   //  8 KB each
    __shared__ __align__(16) ushort Bs[2][256 * 32];   // 16 KB each

    const int tid  = threadIdx.x;
    const int lane = tid & 63;
    const int wave = tid >> 6;
    const int wr = wave >> 2, wc = wave & 3;
    const int bm = blockIdx.y, bn = blockIdx.x;
    const int quad = lane >> 4, r16 = lane & 15;

    const int srow  = tid >> 2;
    const int skoff = (tid & 3) * 8;
    const ushort* Ag16 = Az + (size_t)(bm * 128 + srow) * DIM + skoff;
    const ushort* Bg0  = Bw + (size_t)(bn * 256 + srow) * DIM + skoff;
    const ushort* Bg1  = Bg0 + (size_t)128 * DIM;

    // per-thread fixed row -> fixed (g, tau); factors c_h^tau as named scalars
    const int m   = bm * 128 + srow;
    const int tau = m & (CHUNK - 1);
    const float* Gc = G + (size_t)(m >> 6) * 512;
    const float t1 = (float)tau;
    float fc0,fc1,fc2,fc3,fc4,fc5,fc6,fc7;
    {
        float a, c;
        a = 1.f/(1.f+expf(-alpha_param[0])); c = 1.f - a; fc0 = exp2f(t1 * log2f(c));
        a = 1.f/(1.f+expf(-alpha_param[1])); c = 1.f - a; fc1 = exp2f(t1 * log2f(c));
        a = 1.f/(1.f+expf(-alpha_param[2])); c = 1.f - a; fc2 = exp2f(t1 * log2f(c));
        a = 1.f/(1.f+expf(-alpha_param[3])); c = 1.f - a; fc3 = exp2f(t1 * log2f(c));
        a = 1.f/(1.f+expf(-alpha_param[4])); c = 1.f - a; fc4 = exp2f(t1 * log2f(c));
        a = 1.f/(1.f+expf(-alpha_param[5])); c = 1.f - a; fc5 = exp2f(t1 * log2f(c));
        a = 1.f/(1.f+expf(-alpha_param[6])); c = 1.f - a; fc6 = exp2f(t1 * log2f(c));
        a = 1.f/(1.f+expf(-alpha_param[7])); c = 1.f - a; fc7 = exp2f(t1 * log2f(c));
    }
    auto selfac = [&](int hh) -> float {
        float f = fc0;
        f = (hh == 1) ? fc1 : f;
        f = (hh == 2) ? fc2 : f;
        f = (hh == 3) ? fc3 : f;
        f = (hh == 4) ? fc4 : f;
        f = (hh == 5) ? fc5 : f;
        f = (hh == 6) ? fc6 : f;
        f = (hh == 7) ? fc7 : f;
        return f;
    };
    auto fixpack = [&](usx8 av, float4 z0, float4 z1, float fac) {
        usx8 w;
        w[0] = f2bf(bf2f(av[0]) + fac * z0.x);
        w[1] = f2bf(bf2f(av[1]) + fac * z0.y);
        w[2] = f2bf(bf2f(av[2]) + fac * z0.z);
        w[3] = f2bf(bf2f(av[3]) + fac * z0.w);
        w[4] = f2bf(bf2f(av[4]) + fac * z1.x);
        w[5] = f2bf(bf2f(av[5]) + fac * z1.y);
        w[6] = f2bf(bf2f(av[6]) + fac * z1.z);
        w[7] = f2bf(bf2f(av[7]) + fac * z1.w);
        return w;
    };

    f32x4 acc[4][4];
    #pragma unroll
    for (int i = 0; i < 4; i++)
        #pragma unroll
        for (int j = 0; j < 4; j++)
            acc[i][j] = f32x4{0.f, 0.f, 0.f, 0.f};

    const int nIter = DIM / 32;

    auto stageB = [&](int k0, int b) {
        GLDS(Bg0 + k0, &Bs[b][tid * 8]);
        GLDS(Bg1 + k0, &Bs[b][128 * 32 + tid * 8]);
    };

    // prologue
    stageB(0, 0);
    {
        usx8 av = *(const usx8*)(Ag16);
        float4 z0 = *(const float4*)&Gc[skoff];
        float4 z1 = *(const float4*)&Gc[skoff + 4];
        *(usx8*)&As[0][tid * 8] = fixpack(av, z0, z1, selfac(skoff >> 6));
    }

    int buf = 0;
    for (int k = 0; k < nIter; ++k) {
        __syncthreads();

        usx8 av_n; float4 zn0, zn1; float fac_n = 0.f;
        const bool more = (k + 1 < nIter);
        if (more) {
            const int ko = (k + 1) * 32;
            stageB(ko, buf ^ 1);
            av_n = *(const usx8*)(Ag16 + ko);
            const int dbase = ko + skoff;
            zn0 = *(const float4*)&Gc[dbase];
            zn1 = *(const float4*)&Gc[dbase + 4];
            fac_n = selfac(dbase >> 6);
        }

        bf16x8 af[4], bfr[4];
        #pragma unroll
        for (int i = 0; i < 4; i++)
            af[i] = *(const bf16x8*)&As[buf][(wr * 64 + i * 16 + r16) * 32 + quad * 8];
        #pragma unroll
        for (int j = 0; j < 4; j++)
            bfr[j] = *(const bf16x8*)&Bs[buf][(wc * 64 + j * 16 + r16) * 32 + quad * 8];

        #pragma unroll
        for (int i = 0; i < 4; i++)
            #pragma unroll
            for (int j = 0; j < 4; j++)
                acc[i][j] = __builtin_amdgcn_mfma_f32_16x16x32_bf16(
                                bfr[j], af[i], acc[i][j], 0, 0, 0);  // swapped

        if (more)
            *(usx8*)&As[buf ^ 1][tid * 8] = fixpack(av_n, zn0, zn1, fac_n);
        buf ^= 1;
    }

    // epilogue: m = lane&15 (per i-tile), n = quad*4 + reg
    #pragma unroll
    for (int i = 0; i < 4; i++) {
        const int mr = bm * 128 + wr * 64 + i * 16 + r16;
        #pragma unroll
        for (int j = 0; j < 4; j++) {
            const int n0 = bn * 256 + wc * 64 + j * 16 + quad * 4;
            const float4 bv = *(const float4*)&bias[n0];
            float4 v = make_float4(acc[i][j][0] + bv.x, acc[i][j][1] + bv.y,
                                   acc[i][j][2] + bv.z, acc[i][j][3] + bv.w);
            *(float4*)&Cout[(size_t)mr * DIM + n0] = v;
        }
    }
}

extern "C" void kernel_launch(void* const* d_in, const int* in_sizes, int n_in,
                              void* d_out, int out_size, void* d_ws, size_t ws_size,
                              hipStream_t stream) {
    const float* x           = (const float*)d_in[0];
    const float* W_in        = (const float*)d_in[1];
    const float* b_in        = (const float*)d_in[2];
    const float* W_out       = (const float*)d_in[3];
    const float* b_out       = (const float*)d_in[4];
    const float* init_state  = (const float*)d_in[5];
    const float* alpha_param = (const float*)d_in[6];
    float* out = (float*)d_out;

    // workspace layout
    ushort* z_bf    = (ushort*)d_ws;                       // 32 MB
    ushort* win_bf  = z_bf   + (size_t)MROWS * DIM;        // 0.5 MB
    ushort* wout_bf = win_bf + (size_t)DIM * DIM;          // 0.5 MB (contig after win)
    float*  Lfin    = (float*)(wout_bf + (size_t)DIM * DIM);        // [512][512]
    float*  XpT     = Lfin + (size_t)NGCHUNK * 512;                 // [513][512]
    float*  G       = XpT  + (size_t)(NGCHUNK + 1) * 512;           // [512][512]

    // convert both weight matrices to bf16 (GEMM B operands via GLDS)
    const int nw4 = (DIM * DIM) / 4;          // 65,536
    weights_to_bf16_kernel<<<(2 * nw4 + 255) / 256, 256, 0, stream>>>(
        W_in, W_out, win_bf, nw4);

    // GEMM1 (A fp32 reg-staged, B bf16 GLDS) + fused chunk-local scan
    dim3 g1(2, MROWS / 128);                  // (2, 256)
    gemm1_scan_kernel<<<g1, 512, 0, stream>>>(
        x, win_bf, b_in, alpha_param, z_bf, Lfin, XpT);

    // cross-chunk carry -> G
    scan_fixg_kernel<<<NCHAN / 256, 256, 0, stream>>>(
        Lfin, XpT, alpha_param, init_state, G);

    // GEMM2 with fused carry application
    dim3 g2(2, MROWS / 128);                  // (2, 256)
    gemm2_kernel<<<g2, 512, 0, stream>>>(
        z_bf, wout_bf, b_out, out, G, alpha_param);
}

// Round 6
// 177.030 us; speedup vs baseline: 1.2022x; 1.1098x over previous
//
#include <hip/hip_runtime.h>
#include <stdint.h>

// Problem constants (from reference): B=4, N=8192, D=512, H=8, Dh=64
#define SEQ      8192
#define BATCH    4
#define DIM      512
#define MROWS    32768      // BATCH*SEQ
#define CHUNK    64
#define NCHUNK   128        // SEQ / CHUNK (per batch); 512 global chunks
#define NCHAN    2048       // BATCH * DIM
#define NHEAD    8
#define NGCHUNK  512        // BATCH * NCHUNK
#define XLD      264        // X tile row stride (256 + 8 pad)
#define NITER    16         // DIM / 32 K-steps

typedef unsigned short ushort;
typedef unsigned int   uint;
typedef __bf16 bf16x8 __attribute__((ext_vector_type(8)));
typedef float  f32x4  __attribute__((ext_vector_type(4)));
typedef ushort usx8   __attribute__((ext_vector_type(8)));

// native RNE f32->bf16 (hardware cvt)
__device__ __forceinline__ ushort f2bf(float f) {
    union { __bf16 h; ushort u; } cv;
    cv.h = (__bf16)f;
    return cv.u;
}
__device__ __forceinline__ float bf2f(ushort v) {
    return __uint_as_float(((unsigned)v) << 16);
}

// both weight matrices in one launch; outputs contiguous (win_bf then wout_bf)
__global__ void weights_to_bf16_kernel(const float* __restrict__ w_in,
                                       const float* __restrict__ w_out,
                                       ushort* __restrict__ dst, int n4each) {
    int i = blockIdx.x * blockDim.x + threadIdx.x;
    if (i >= 2 * n4each) return;
    const float4* src = (i < n4each) ? (const float4*)w_in
                                     : (const float4*)w_out - n4each;
    float4 v = src[i];
    ushort4 r;
    r.x = f2bf(v.x); r.y = f2bf(v.y); r.z = f2bf(v.z); r.w = f2bf(v.w);
    ((ushort4*)dst)[i] = r;
}

#define GLDS(g, l) __builtin_amdgcn_global_load_lds(                        \
        (const __attribute__((address_space(1))) void*)(g),                 \
        (__attribute__((address_space(3))) void*)(l), 16, 0, 0)

#define WAITV(n)  asm volatile("s_waitcnt vmcnt(" #n ")" ::: "memory")
#define WAITL0()  asm volatile("s_waitcnt lgkmcnt(0)" ::: "memory")
#define BAR()     do { __builtin_amdgcn_s_barrier();                        \
                       __builtin_amdgcn_sched_barrier(0); } while (0)
#define SBAR()    __builtin_amdgcn_sched_barrier(0)

// =====================================================================
// GEMM1 + fused chunk-local scan
//   xp = x @ W_in^T + b_in  (tile kept in LDS, never written to global)
//   z_loc'[t] = c*z' + alpha*(xp[t]-xp[t-1]), prev=0 at chunk start
//   writes: z_loc' (bf16), L' = chunk tail (f32), XpT[g+1] = xp tail (f32)
//   Cross-chunk carry applied in GEMM2: z = z_loc' + c^tau * G.
// K-loop: 3-buffer rotation, counted vmcnt, raw s_barrier.
// RACE FIX vs round 5: stage-issue (P1) moved AFTER the barrier, so the
// GLDS overwrite of buf (k+2)%3 is ordered after ALL waves' iter k-1 reads
// of that buffer (reads complete before each wave reaches BAR(k)).
// Per iter: P2(ds_write buf k+1) -> WAITV -> lgkm0 -> BAR -> P1(issue buf
// k+2: A->regs [pin] B->GLDS) -> ds_read buf k -> MFMA.
// Binding vm-wait is the compiler's reg-dep wait at P2 (1-iter-old A loads),
// which also retires the 2-iter-old B GLDS; WAITV(4) is a backstop.
// =====================================================================
__global__ __launch_bounds__(512, 4) void gemm1_scan_kernel(
        const float* __restrict__ x,    const ushort* __restrict__ Bw,
        const float* __restrict__ b_in, const float* __restrict__ alpha_param,
        ushort* __restrict__ zout,
        float* __restrict__ Lfin,       float* __restrict__ XpT)
{
    // LDS: 3x(8KB As + 16KB Bs) = 72 KB, overlaid with X[128][XLD] (66 KB)
    __shared__ __align__(16) char smem[73728];
    ushort* As0 = (ushort*)smem;                 // 3 bufs x 4096 ushorts
    ushort* Bs0 = (ushort*)(smem + 24576);       // 3 bufs x 8192 ushorts
    ushort* X   = (ushort*)smem;                 // [128][XLD] (epilogue)

    const int tid = threadIdx.x;            // 0..511
    const int bn  = blockIdx.x;             // 0..1
    const int bm  = blockIdx.y;             // 0..255

    const int lane = tid & 63;
    const int wave = tid >> 6;
    const int wr = wave >> 2, wc = wave & 3;
    const int quad = lane >> 4, r16 = lane & 15;

    // staging map: thread -> row = tid>>2 (0..127), k-off = (tid&3)*8
    const int srow  = tid >> 2;
    const int skoff = (tid & 3) * 8;
    const float*  Ag  = x  + (size_t)(bm * 128 + srow) * DIM + skoff;
    const ushort* Bg0 = Bw + (size_t)(bn * 256 + srow) * DIM + skoff;
    const ushort* Bg1 = Bg0 + (size_t)128 * DIM;

    f32x4 acc[4][4];
    #pragma unroll
    for (int i = 0; i < 4; i++)
        #pragma unroll
        for (int j = 0; j < 4; j++)
            acc[i][j] = f32x4{0.f, 0.f, 0.f, 0.f};

    auto stageB = [&](int k0, int b) {
        GLDS(Bg0 + k0, &Bs0[b * 8192 + tid * 8]);
        GLDS(Bg1 + k0, &Bs0[b * 8192 + 4096 + tid * 8]);
    };
    auto packA = [&](float4 lo, float4 hi) {
        usx8 w;
        w[0] = f2bf(lo.x); w[1] = f2bf(lo.y); w[2] = f2bf(lo.z); w[3] = f2bf(lo.w);
        w[4] = f2bf(hi.x); w[5] = f2bf(hi.y); w[6] = f2bf(hi.z); w[7] = f2bf(hi.w);
        return w;
    };

    // A reg sets: data for buf j lives in set (j&1)
    float4 aLo0, aHi0, aLo1, aHi1;

    // prologue: issue stages for bufs 0 and 1; write As[0]
    aLo0 = *(const float4*)(Ag);      aHi0 = *(const float4*)(Ag + 4);
    stageB(0, 0);
    aLo1 = *(const float4*)(Ag + 32); aHi1 = *(const float4*)(Ag + 36);
    stageB(32, 1);
    *(usx8*)&As0[tid * 8] = packA(aLo0, aHi0);   // compiler auto-waits regs

    #pragma unroll
    for (int k = 0; k < NITER; ++k) {
        const int cur = k % 3;
        const int stg = (k + 2) % 3;
        const int wnx = (k + 1) % 3;

        // P2: ds_write A for buf k+1 (regs loaded at iter k-1 / prologue).
        // Safe pre-BAR: As[wnx] last read at iter k-2 (2 barriers back).
        if (k + 1 < NITER) {
            usx8 w = ((k & 1) == 0) ? packA(aLo1, aHi1) : packA(aLo0, aHi0);
            *(usx8*)&As0[wnx * 4096 + tid * 8] = w;
        }
        // counted vm backstop + lgkm drain (own ds_write) + rendezvous
        if (k < NITER - 1) WAITV(4); else WAITV(0);
        WAITL0();
        BAR();

        // P1 (POST-BAR): issue stage for buf k+2. A-loads pinned before
        // GLDS so P2's reg-dep wait next iter retires the older GLDS too.
        if (k + 2 < NITER) {
            const int ko = (k + 2) * 32;
            if ((k & 1) == 0) {
                aLo0 = *(const float4*)(Ag + ko); aHi0 = *(const float4*)(Ag + ko + 4);
            } else {
                aLo1 = *(const float4*)(Ag + ko); aHi1 = *(const float4*)(Ag + ko + 4);
            }
            SBAR();
            stageB(ko, stg);
        }

        bf16x8 af[4], bfr[4];
        #pragma unroll
        for (int i = 0; i < 4; i++)
            af[i] = *(const bf16x8*)&As0[cur * 4096 + (wr * 64 + i * 16 + r16) * 32 + quad * 8];
        #pragma unroll
        for (int j = 0; j < 4; j++)
            bfr[j] = *(const bf16x8*)&Bs0[cur * 8192 + (wc * 64 + j * 16 + r16) * 32 + quad * 8];

        #pragma unroll
        for (int i = 0; i < 4; i++)
            #pragma unroll
            for (int j = 0; j < 4; j++)
                acc[i][j] = __builtin_amdgcn_mfma_f32_16x16x32_bf16(
                                bfr[j], af[i], acc[i][j], 0, 0, 0);  // swapped
    }

    // ---- epilogue part 1: xp tile (C + bias) -> LDS X[128][XLD] (bf16)
    __syncthreads();   // full drain; all waves done reading As/Bs
    #pragma unroll
    for (int i = 0; i < 4; i++) {
        const int ml = wr * 64 + i * 16 + r16;
        #pragma unroll
        for (int j = 0; j < 4; j++) {
            const int nl = wc * 64 + j * 16 + quad * 4;
            const float4 bv = *(const float4*)&b_in[bn * 256 + nl];
            ushort4 r4;
            r4.x = f2bf(acc[i][j][0] + bv.x);
            r4.y = f2bf(acc[i][j][1] + bv.y);
            r4.z = f2bf(acc[i][j][2] + bv.z);
            r4.w = f2bf(acc[i][j][3] + bv.w);
            *(ushort4*)&X[ml * XLD + nl] = r4;
        }
    }
    __syncthreads();

    // ---- epilogue part 2: chunk-local scan (prev = 0 at chunk start)
    const int chalf = tid >> 8;             // 0..1
    const int cidx  = tid & 255;            // 0..255
    const int g     = 2 * bm + chalf;       // global chunk 0..511
    const int d     = bn * 256 + cidx;      // 0..511
    const int h     = d >> 6;
    const float alpha = 1.0f / (1.0f + expf(-alpha_param[h]));
    const float c     = 1.0f - alpha;

    const ushort* Xr  = X + chalf * 64 * XLD + cidx;
    ushort* zrow = zout + ((size_t)(bm * 128 + chalf * 64)) * DIM + d;

    float z = 0.f, prev = 0.f;
    #pragma unroll 8
    for (int r = 0; r < CHUNK; ++r) {
        float xv = bf2f(Xr[r * XLD]);
        z = c * z + alpha * (xv - prev);
        prev = xv;
        zrow[(size_t)r * DIM] = f2bf(z);
    }
    Lfin[(size_t)g * 512 + d]       = z;     // L' tail
    XpT[(size_t)(g + 1) * 512 + d]  = prev;  // xp tail -> next chunk's xpt
}

// =====================================================================
// Carry chain:  G_k = c*Z_k - alpha*xpt_k ;  Z_{k+1} = L'_k + c^63 * G_k
// =====================================================================
__global__ void scan_fixg_kernel(const float* __restrict__ Lfin,
                                 const float* __restrict__ XpT,
                                 const float* __restrict__ alpha_param,
                                 const float* __restrict__ init_state,
                                 float* __restrict__ G)
{
    int ch = blockIdx.x * blockDim.x + threadIdx.x;   // 0..2047
    if (ch >= NCHAN) return;
    const int b = ch >> 9;
    const int d = ch & (DIM - 1);
    const int h = d >> 6;
    const float alpha = 1.0f / (1.0f + expf(-alpha_param[h]));
    const float c = 1.0f - alpha;
    const float c2 = c * c, c4 = c2 * c2, c8 = c4 * c4,
                c16 = c8 * c8, c32 = c16 * c16;
    const float c63 = c32 * c16 * c8 * c4 * c2 * c;
    const float sinit = init_state[d];

    float Z = sinit;
    const float* Lp = Lfin + (size_t)(b * NCHUNK) * 512 + d;
    const float* Xp = XpT  + (size_t)(b * NCHUNK) * 512 + d;
    float*       Gp = G    + (size_t)(b * NCHUNK) * 512 + d;

    constexpr int PF = 16;
    float Lr[PF], Xr[PF];
    #pragma unroll
    for (int j = 0; j < PF; ++j) {
        Lr[j] = Lp[(size_t)j * 512];
        Xr[j] = Xp[(size_t)j * 512];
    }
    for (int gr = 0; gr < NCHUNK / PF; ++gr) {        // 8 groups
        #pragma unroll
        for (int j = 0; j < PF; ++j) {
            const int kl = gr * PF + j;
            const float xpt = (kl == 0) ? sinit : Xr[j];
            const float Lc  = Lr[j];
            if (gr + 1 < NCHUNK / PF) {
                Lr[j] = Lp[(size_t)((gr + 1) * PF + j) * 512];
                Xr[j] = Xp[(size_t)((gr + 1) * PF + j) * 512];
            }
            const float Gv = c * Z - alpha * xpt;
            Gp[(size_t)kl * 512] = Gv;
            Z = Lc + c63 * Gv;
        }
    }
}

// =====================================================================
// GEMM2: out = z @ W_out^T + b_out ; carry correction fused in A-staging:
//   a[tau, d] += c_h^tau * G[g][d]   (g = row>>6, tau = row&63)
// Same race-fixed 3-buffer loop. P1 = 5 vmem ops (z usx8 + 2 G float4 +
// 2 GLDS B) -> backstop WAITV(5), 0 on last iteration.
// =====================================================================
__global__ __launch_bounds__(512, 4) void gemm2_kernel(
        const ushort* __restrict__ Az, const ushort* __restrict__ Bw,
        const float* __restrict__ bias, float* __restrict__ Cout,
        const float* __restrict__ G, const float* __restrict__ alpha_param)
{
    __shared__ __align__(16) char smem[73728];
    ushort* As0 = (ushort*)smem;                 // 3 bufs x 4096 ushorts
    ushort* Bs0 = (ushort*)(smem + 24576);       // 3 bufs x 8192 ushorts

    const int tid  = threadIdx.x;
    const int lane = tid & 63;
    const int wave = tid >> 6;
    const int wr = wave >> 2, wc = wave & 3;
    const int bm = blockIdx.y, bn = blockIdx.x;
    const int quad = lane >> 4, r16 = lane & 15;

    const int srow  = tid >> 2;
    const int skoff = (tid & 3) * 8;
    const ushort* Ag16 = Az + (size_t)(bm * 128 + srow) * DIM + skoff;
    const ushort* Bg0  = Bw + (size_t)(bn * 256 + srow) * DIM + skoff;
    const ushort* Bg1  = Bg0 + (size_t)128 * DIM;

    // per-thread fixed row -> fixed (g, tau); c_h^tau as named scalars
    const int m   = bm * 128 + srow;
    const int tau = m & (CHUNK - 1);
    const float* Gc = G + (size_t)(m >> 6) * 512;
    const float t1 = (float)tau;
    float fc0,fc1,fc2,fc3,fc4,fc5,fc6,fc7;
    {
        float a, c;
        a = 1.f/(1.f+expf(-alpha_param[0])); c = 1.f - a; fc0 = exp2f(t1 * log2f(c));
        a = 1.f/(1.f+expf(-alpha_param[1])); c = 1.f - a; fc1 = exp2f(t1 * log2f(c));
        a = 1.f/(1.f+expf(-alpha_param[2])); c = 1.f - a; fc2 = exp2f(t1 * log2f(c));
        a = 1.f/(1.f+expf(-alpha_param[3])); c = 1.f - a; fc3 = exp2f(t1 * log2f(c));
        a = 1.f/(1.f+expf(-alpha_param[4])); c = 1.f - a; fc4 = exp2f(t1 * log2f(c));
        a = 1.f/(1.f+expf(-alpha_param[5])); c = 1.f - a; fc5 = exp2f(t1 * log2f(c));
        a = 1.f/(1.f+expf(-alpha_param[6])); c = 1.f - a; fc6 = exp2f(t1 * log2f(c));
        a = 1.f/(1.f+expf(-alpha_param[7])); c = 1.f - a; fc7 = exp2f(t1 * log2f(c));
    }
    auto selfac = [&](int hh) -> float {
        float f = fc0;
        f = (hh == 1) ? fc1 : f;
        f = (hh == 2) ? fc2 : f;
        f = (hh == 3) ? fc3 : f;
        f = (hh == 4) ? fc4 : f;
        f = (hh == 5) ? fc5 : f;
        f = (hh == 6) ? fc6 : f;
        f = (hh == 7) ? fc7 : f;
        return f;
    };
    auto fixpack = [&](usx8 av, float4 z0, float4 z1, float fac) {
        usx8 w;
        w[0] = f2bf(bf2f(av[0]) + fac * z0.x);
        w[1] = f2bf(bf2f(av[1]) + fac * z0.y);
        w[2] = f2bf(bf2f(av[2]) + fac * z0.z);
        w[3] = f2bf(bf2f(av[3]) + fac * z0.w);
        w[4] = f2bf(bf2f(av[4]) + fac * z1.x);
        w[5] = f2bf(bf2f(av[5]) + fac * z1.y);
        w[6] = f2bf(bf2f(av[6]) + fac * z1.z);
        w[7] = f2bf(bf2f(av[7]) + fac * z1.w);
        return w;
    };

    f32x4 acc[4][4];
    #pragma unroll
    for (int i = 0; i < 4; i++)
        #pragma unroll
        for (int j = 0; j < 4; j++)
            acc[i][j] = f32x4{0.f, 0.f, 0.f, 0.f};

    auto stageB = [&](int k0, int b) {
        GLDS(Bg0 + k0, &Bs0[b * 8192 + tid * 8]);
        GLDS(Bg1 + k0, &Bs0[b * 8192 + 4096 + tid * 8]);
    };

    // A reg sets: data for buf j in set (j&1)
    usx8 av0, av1; float4 g0lo, g0hi, g1lo, g1hi;

    // prologue: issue stages for bufs 0,1; write fixed As[0]
    av0 = *(const usx8*)(Ag16);
    g0lo = *(const float4*)&Gc[skoff]; g0hi = *(const float4*)&Gc[skoff + 4];
    stageB(0, 0);
    av1 = *(const usx8*)(Ag16 + 32);
    g1lo = *(const float4*)&Gc[32 + skoff]; g1hi = *(const float4*)&Gc[32 + skoff + 4];
    stageB(32, 1);
    *(usx8*)&As0[tid * 8] = fixpack(av0, g0lo, g0hi, selfac(skoff >> 6));

    #pragma unroll
    for (int k = 0; k < NITER; ++k) {
        const int cur = k % 3;
        const int stg = (k + 2) % 3;
        const int wnx = (k + 1) % 3;

        // P2: ds_write fixed A for buf k+1 (regs loaded at iter k-1)
        if (k + 1 < NITER) {
            const float fac = selfac((((k + 1) * 32) + skoff) >> 6);
            usx8 w = ((k & 1) == 0) ? fixpack(av1, g1lo, g1hi, fac)
                                    : fixpack(av0, g0lo, g0hi, fac);
            *(usx8*)&As0[wnx * 4096 + tid * 8] = w;
        }
        if (k < NITER - 1) WAITV(5); else WAITV(0);
        WAITL0();
        BAR();

        // P1 (POST-BAR): issue stage for buf k+2
        if (k + 2 < NITER) {
            const int ko = (k + 2) * 32;
            if ((k & 1) == 0) {
                av0 = *(const usx8*)(Ag16 + ko);
                g0lo = *(const float4*)&Gc[ko + skoff];
                g0hi = *(const float4*)&Gc[ko + skoff + 4];
            } else {
                av1 = *(const usx8*)(Ag16 + ko);
                g1lo = *(const float4*)&Gc[ko + skoff];
                g1hi = *(const float4*)&Gc[ko + skoff + 4];
            }
            SBAR();
            stageB(ko, stg);
        }

        bf16x8 af[4], bfr[4];
        #pragma unroll
        for (int i = 0; i < 4; i++)
            af[i] = *(const bf16x8*)&As0[cur * 4096 + (wr * 64 + i * 16 + r16) * 32 + quad * 8];
        #pragma unroll
        for (int j = 0; j < 4; j++)
            bfr[j] = *(const bf16x8*)&Bs0[cur * 8192 + (wc * 64 + j * 16 + r16) * 32 + quad * 8];

        #pragma unroll
        for (int i = 0; i < 4; i++)
            #pragma unroll
            for (int j = 0; j < 4; j++)
                acc[i][j] = __builtin_amdgcn_mfma_f32_16x16x32_bf16(
                                bfr[j], af[i], acc[i][j], 0, 0, 0);  // swapped
    }

    // epilogue: m = lane&15 (per i-tile), n = quad*4 + reg
    #pragma unroll
    for (int i = 0; i < 4; i++) {
        const int mr = bm * 128 + wr * 64 + i * 16 + r16;
        #pragma unroll
        for (int j = 0; j < 4; j++) {
            const int n0 = bn * 256 + wc * 64 + j * 16 + quad * 4;
            const float4 bv = *(const float4*)&bias[n0];
            float4 v = make_float4(acc[i][j][0] + bv.x, acc[i][j][1] + bv.y,
                                   acc[i][j][2] + bv.z, acc[i][j][3] + bv.w);
            *(float4*)&Cout[(size_t)mr * DIM + n0] = v;
        }
    }
}

extern "C" void kernel_launch(void* const* d_in, const int* in_sizes, int n_in,
                              void* d_out, int out_size, void* d_ws, size_t ws_size,
                              hipStream_t stream) {
    const float* x           = (const float*)d_in[0];
    const float* W_in        = (const float*)d_in[1];
    const float* b_in        = (const float*)d_in[2];
    const float* W_out       = (const float*)d_in[3];
    const float* b_out       = (const float*)d_in[4];
    const float* init_state  = (const float*)d_in[5];
    const float* alpha_param = (const float*)d_in[6];
    float* out = (float*)d_out;

    // workspace layout
    ushort* z_bf    = (ushort*)d_ws;                       // 32 MB
    ushort* win_bf  = z_bf   + (size_t)MROWS * DIM;        // 0.5 MB
    ushort* wout_bf = win_bf + (size_t)DIM * DIM;          // 0.5 MB
    float*  Lfin    = (float*)(wout_bf + (size_t)DIM * DIM);        // [512][512]
    float*  XpT     = Lfin + (size_t)NGCHUNK * 512;                 // [513][512]
    float*  G       = XpT  + (size_t)(NGCHUNK + 1) * 512;           // [512][512]

    const int nw4 = (DIM * DIM) / 4;          // 65,536
    weights_to_bf16_kernel<<<(2 * nw4 + 255) / 256, 256, 0, stream>>>(
        W_in, W_out, win_bf, nw4);

    dim3 g1(2, MROWS / 128);                  // (2, 256)
    gemm1_scan_kernel<<<g1, 512, 0, stream>>>(
        x, win_bf, b_in, alpha_param, z_bf, Lfin, XpT);

    scan_fixg_kernel<<<NCHAN / 256, 256, 0, stream>>>(
        Lfin, XpT, alpha_param, init_state, G);

    dim3 g2(2, MROWS / 128);                  // (2, 256)
    gemm2_kernel<<<g2, 512, 0, stream>>>(
        z_bf, wout_bf, b_out, out, G, alpha_param);
}